// Round 11
// baseline (2178.676 us; speedup 1.0000x reference)
//
#include <hip/hip_runtime.h>
#include <hip/hip_bf16.h>

// Problem constants
#define TT 2048
#define KK 6
#define EE 32
#define DD 2048
#define FF 1408
#define SS 2
#define CC 384   // TT*KK/EE

typedef __bf16 bf16_t;
typedef __attribute__((ext_vector_type(8))) __bf16 bf16x8;
typedef __attribute__((ext_vector_type(4))) float f32x4;
typedef unsigned int u32;

#define AS1 __attribute__((address_space(1)))
#define AS3 __attribute__((address_space(3)))

__device__ __forceinline__ u32 f2bf(float f) {
    u32 u = __builtin_bit_cast(u32, f);
    return (u + 0x7fffu + ((u >> 16) & 1u)) >> 16;   // RNE, no NaN in data
}
__device__ __forceinline__ u32 pack2(float a, float b) {
    return f2bf(a) | (f2bf(b) << 16);
}
__device__ __forceinline__ float silu_mul(float g, float u) {
    return (g / (1.0f + __expf(-g))) * u;
}

// ---------------- dispatch: pair -> slot (balanced: exactly CC per expert) ----
__global__ void k_dispatch(const int* __restrict__ idx, int* __restrict__ counts,
                           int* __restrict__ tok, int* __restrict__ sop) {
    int p = blockIdx.x * 256 + threadIdx.x;
    if (p >= TT * KK) return;
    int e = idx[p];
    int pos = atomicAdd(&counts[e], 1);
    int slot = e * CC + pos;
    tok[slot] = p / KK;
    sop[p] = slot;
}

// ---------------- gather + fp32->bf16 convert --------------------------------
__global__ void k_gather(const float* __restrict__ x, const int* __restrict__ tok,
                         bf16_t* __restrict__ xall) {
    int row = blockIdx.x;
    int srow = (row < EE * CC) ? tok[row] : (row - EE * CC);
    const float* src = x + (size_t)srow * DD;
    bf16_t* dst = xall + (size_t)row * DD;
    int c0 = threadIdx.x * 8;
    float4 a = *(const float4*)(src + c0);
    float4 b = *(const float4*)(src + c0 + 4);
    uint4 o;
    o.x = pack2(a.x, a.y); o.y = pack2(a.z, a.w);
    o.z = pack2(b.x, b.y); o.w = pack2(b.z, b.w);
    *(uint4*)(dst + c0) = o;
}

// =====================================================================
// Routed grouped GEMM: B-read-once + MAX independent barrier groups.
// Block = (expert, N=32 slab), 256 threads (4 waves), M=384 (whole expert),
// wave-tile 96x32 -> acc[6][2] = 48 VGPR, total ~110 -> 4 blocks/CU
// (launch_bounds(256,4)). A-fragments read DIRECTLY from global (bf16,
// L2/L3-resident, 16B/lane) -- NO A LDS, so LDS = B dbuf only (4.6 KB).
// Loop: single barrier/iter, 2-phase B dbuf (load regs early, write other
// buffer late), no inline asm -- compiler schedules (R0/R9-proven regime,
// ~2.9 TB/s class). B (fp32 weights) read exactly once per expert.
// =====================================================================
template<bool FUSED>
__global__ __launch_bounds__(256, 4) void k_gemm_r(
    const bf16_t* __restrict__ Aall, const float* __restrict__ Br,
    bf16_t* __restrict__ Out, int Kdim, int Bstr, int Ostr, int NB)
{
    const int lin = blockIdx.x;
    const int xcd = lin & 7, jj = lin >> 3;
    const int e = xcd + 8 * (jj / NB);     // expert pinned to XCD e%8
    const int nblk = jj % NB;

    const bf16_t* A = Aall + (size_t)e * CC * Kdim;
    const float* Bbase = Br + (size_t)e * Kdim * Bstr;

    const int tid = threadIdx.x;
    const int lane = tid & 63, wid = tid >> 6;
    const int m_base = wid * 96;               // 4 waves x 96 rows = 384
    const int l15 = lane & 15, lq = lane >> 4;
    const int bn = tid & 31, kr = tid >> 5;    // B-stage: col 0..31, k-group 0..7

    const float* bsrc;
    bf16_t* Cout;
    if (FUSED) {   // slab = 16 gate cols + 16 up cols (same local index)
        bsrc = Bbase + ((bn & 16) ? FF : 0) + nblk * 16 + (bn & 15);
        Cout = Out + (size_t)e * CC * Ostr + nblk * 16;
    } else {
        bsrc = Bbase + nblk * 32 + bn;
        Cout = Out + (size_t)e * CC * Ostr + nblk * 32;
    }

    __shared__ __align__(16) bf16_t Bs[2][32 * 36];   // 2 x 2.3 KB

    f32x4 acc[6][2] = {};
    const int ks = Kdim >> 5;   // 64 (gate_up) or 44 (down)

    float v[4];
    auto loadB = [&](int kt) {
        const float* sp = bsrc + (size_t)(kt * 32 + kr * 4) * Bstr;
        #pragma unroll
        for (int t = 0; t < 4; ++t) v[t] = sp[(size_t)t * Bstr];
    };
    auto writeB = [&](bf16_t* bbuf) {
        uint2 w;
        w.x = pack2(v[0], v[1]); w.y = pack2(v[2], v[3]);
        *(uint2*)(bbuf + bn * 36 + kr * 4) = w;
    };
    auto compute = [&](const bf16_t* bbuf, int k0) {
        bf16x8 bfr[2];
        #pragma unroll
        for (int j = 0; j < 2; ++j)
            bfr[j] = *(const bf16x8*)(bbuf + (j * 16 + l15) * 36 + lq * 8);
        #pragma unroll
        for (int m = 0; m < 6; ++m) {
            const bf16x8 af = *(const bf16x8*)(A
                + (size_t)(m_base + m * 16 + l15) * Kdim + k0 + lq * 8);
            #pragma unroll
            for (int j = 0; j < 2; ++j)
                acc[m][j] = __builtin_amdgcn_mfma_f32_16x16x32_bf16(af, bfr[j], acc[m][j], 0, 0, 0);
        }
    };

    loadB(0);
    writeB(&Bs[0][0]);
    __syncthreads();
    for (int t = 0; t < ks; ++t) {
        if (t + 1 < ks) loadB(t + 1);                 // B(t+1) -> regs (early)
        compute(&Bs[t & 1][0], t << 5);               // MFMA on buf[t&1]
        if (t + 1 < ks) writeB(&Bs[(t + 1) & 1][0]);  // regs -> other buf (late)
        __syncthreads();
    }

    // ---- epilogue: C/D layout col=lane&15, row=quad*4+reg ----
    if (FUSED) {
        #pragma unroll
        for (int m = 0; m < 6; ++m)
            #pragma unroll
            for (int rr = 0; rr < 4; ++rr) {
                const int mm = m_base + m * 16 + lq * 4 + rr;
                Cout[(size_t)mm * Ostr + l15] =
                    (bf16_t)silu_mul(acc[m][0][rr], acc[m][1][rr]);
            }
    } else {
        #pragma unroll
        for (int m = 0; m < 6; ++m)
            #pragma unroll
            for (int j = 0; j < 2; ++j) {
                const int n = j * 16 + l15;
                #pragma unroll
                for (int rr = 0; rr < 4; ++rr) {
                    const int mm = m_base + m * 16 + lq * 4 + rr;
                    Cout[(size_t)mm * Ostr + n] = (bf16_t)acc[m][j][rr];
                }
            }
    }
}

// =====================================================================
// Shared-expert GEMM. 256 threads (4 waves, 2m x 2n), 128x128, BK=32.
// R8-verified static-ring pipeline, verbatim.
// =====================================================================
#define BSTR 40
template<bool FUSED>
__global__ __launch_bounds__(256) void k_gemm_s(
    const bf16_t* __restrict__ Ash, const float* __restrict__ Bsh,
    bf16_t* __restrict__ Out, int Kdim, int Bstr, int Ostr, int ash_stride,
    int nkeys, int KQ, int NBs)
{
    const int b = blockIdx.x;
    const int xcd = b & 7, jj = b >> 3;
    const int m = jj / KQ, kqi = jj % KQ;
    const int key = kqi * 8 + xcd;
    if (key >= nkeys) return;
    const int s = key / NBs, nb = key % NBs;

    const bf16_t* A = Ash + ((size_t)s * ash_stride + (size_t)m * 128) * Kdim;
    const float* Bp = Bsh + (size_t)s * Kdim * Bstr;

    const int tid = threadIdx.x;
    const int lane = tid & 63, wid = tid >> 6;
    const int m_off = (wid >> 1) * 64, wn = wid & 1;
    const int l15 = lane & 15, lq = lane >> 4;
    const int arow = tid >> 2, ac = tid & 3;
    const int bn = tid & 127, kh = tid >> 7;

    const float* bsrc;
    bf16_t* Cout;
    if (FUSED) {
        bsrc = Bp + ((bn & 64) ? FF : 0) + nb * 64 + (bn & 63);
        Cout = Out + ((size_t)s * TT + (size_t)m * 128) * Ostr + nb * 64;
    } else {
        bsrc = Bp + nb * 128 + bn;
        Cout = Out + ((size_t)s * TT + (size_t)m * 128) * Ostr + nb * 128;
    }

    __shared__ __align__(16) bf16_t As[2][128 * 32];
    __shared__ __align__(16) bf16_t Bs[2][128 * BSTR];

    f32x4 acc[4][4] = {};
    const int ks = Kdim >> 5;

    auto stageA = [&](int kt, bf16_t* dst) {
        const int k0 = kt << 5;
        #pragma unroll
        for (int i = 0; i < 2; ++i) {
            const int row = i * 64 + arow;
            const int c = ac ^ (arow & 3);
            const bf16_t* g = A + (size_t)row * Kdim + (k0 + c * 8);
            AS3 u32* l = (AS3 u32*)(void*)(dst + (size_t)(i * 64 + wid * 16) * 32);
            __builtin_amdgcn_global_load_lds((const AS1 u32*)(const void*)g, l, 16, 0, 0);
        }
    };
    auto loadB = [&](int kt, float* v) {
        const float* sp = bsrc + (size_t)((kt << 5) + kh * 16) * Bstr;
        #pragma unroll
        for (int t = 0; t < 16; ++t) v[t] = sp[(size_t)t * Bstr];
    };
    auto writeB = [&](bf16_t* bbuf, const float* v) {
        u32 p[8];
        #pragma unroll
        for (int t = 0; t < 8; ++t) p[t] = pack2(v[2 * t], v[2 * t + 1]);
        uint4 w0, w1;
        w0.x = p[0]; w0.y = p[1]; w0.z = p[2]; w0.w = p[3];
        w1.x = p[4]; w1.y = p[5]; w1.z = p[6]; w1.w = p[7];
        *(uint4*)(bbuf + (size_t)bn * BSTR + kh * 16) = w0;
        *(uint4*)(bbuf + (size_t)bn * BSTR + kh * 16 + 8) = w1;
    };
    auto compute = [&](const bf16_t* abuf, const bf16_t* bbuf) {
        bf16x8 af[4], bfr[4];
        #pragma unroll
        for (int i = 0; i < 4; ++i) {
            const int row = m_off + i * 16 + l15;
            af[i] = *(const bf16x8*)(abuf + (size_t)row * 32
                       + (size_t)((lq ^ (row & 3)) * 8));
        }
        #pragma unroll
        for (int j = 0; j < 4; ++j) {
            const int n_ds = FUSED ? (wn * 32 + (j & 1) * 16 + (j >> 1) * 64)
                                   : (wn * 64 + j * 16);
            bfr[j] = *(const bf16x8*)(bbuf + (size_t)(n_ds + l15) * BSTR + lq * 8);
        }
        #pragma unroll
        for (int i = 0; i < 4; ++i)
            #pragma unroll
            for (int j = 0; j < 4; ++j)
                acc[i][j] = __builtin_amdgcn_mfma_f32_16x16x32_bf16(af[i], bfr[j], acc[i][j], 0, 0, 0);
    };

    float r0[16], r1[16], r2[16], r3[16];
    bf16_t* const As0 = &As[0][0];  bf16_t* const As1 = &As[1][0];
    bf16_t* const Bs0 = &Bs[0][0];  bf16_t* const Bs1 = &Bs[1][0];

    loadB(0, r0);
    asm volatile("s_waitcnt vmcnt(0)" ::: "memory");
    writeB(Bs0, r0);
    loadB(1, r1);
    loadB(2, r2);
    stageA(0, As0);
    loadB(3, r3);

#define S_ITER(T, RLOAD, RWRITE, ASC, ASN, BSC, BSN)                      \
    {                                                                     \
        const int tb = ((T) + 4 < ks) ? (T) + 4 : ks - 1;                 \
        loadB(tb, RLOAD);                                                 \
        asm volatile("s_waitcnt vmcnt(32)" ::: "memory");                 \
        asm volatile("s_waitcnt lgkmcnt(0)" ::: "memory");                \
        __builtin_amdgcn_s_barrier();                                     \
        const int tn = ((T) + 1 < ks) ? (T) + 1 : ks - 1;                 \
        stageA(tn, ASN);                                                  \
        compute(ASC, BSC);                                                \
        writeB(BSN, RWRITE);                                              \
    }

    for (int t = 0; t < ks; t += 4) {
        S_ITER(t + 0, r0, r1, As0, As1, Bs0, Bs1);
        S_ITER(t + 1, r1, r2, As1, As0, Bs1, Bs0);
        S_ITER(t + 2, r2, r3, As0, As1, Bs0, Bs1);
        S_ITER(t + 3, r3, r0, As1, As0, Bs1, Bs0);
    }
#undef S_ITER

    if (FUSED) {
        #pragma unroll
        for (int i = 0; i < 4; ++i)
            #pragma unroll
            for (int j = 0; j < 2; ++j) {
                const int n = wn * 32 + j * 16 + l15;
                #pragma unroll
                for (int rr = 0; rr < 4; ++rr) {
                    const int mm = m_off + i * 16 + lq * 4 + rr;
                    Cout[(size_t)mm * Ostr + n] = (bf16_t)silu_mul(acc[i][j][rr], acc[i][j + 2][rr]);
                }
            }
    } else {
        #pragma unroll
        for (int i = 0; i < 4; ++i)
            #pragma unroll
            for (int j = 0; j < 4; ++j) {
                const int n = wn * 64 + j * 16 + l15;
                #pragma unroll
                for (int rr = 0; rr < 4; ++rr) {
                    const int mm = m_off + i * 16 + lq * 4 + rr;
                    Cout[(size_t)mm * Ostr + n] = (bf16_t)acc[i][j][rr];
                }
            }
    }
}

// ---------------- combine: weighted scatter of routed + shared add ----------
__global__ void k_combine(const bf16_t* __restrict__ down, const int* __restrict__ sop,
                          const float* __restrict__ wts, float* __restrict__ y) {
    int t = blockIdx.x;
    int d0 = threadIdx.x * 8;
    float a[8] = {0, 0, 0, 0, 0, 0, 0, 0};
    #pragma unroll
    for (int k = 0; k < KK; ++k) {
        int slot = sop[t * KK + k];
        float w = wts[t * KK + k];
        bf16x8 v = *(const bf16x8*)(down + (size_t)slot * DD + d0);
        #pragma unroll
        for (int j = 0; j < 8; ++j) a[j] += w * (float)v[j];
    }
    #pragma unroll
    for (int s = 0; s < SS; ++s) {
        bf16x8 v = *(const bf16x8*)(down + ((size_t)EE * CC + (size_t)s * TT + t) * DD + d0);
        #pragma unroll
        for (int j = 0; j < 8; ++j) a[j] += (float)v[j];
    }
    float4 o0, o1;
    o0.x = a[0]; o0.y = a[1]; o0.z = a[2]; o0.w = a[3];
    o1.x = a[4]; o1.y = a[5]; o1.z = a[6]; o1.w = a[7];
    *(float4*)(y + (size_t)t * DD + d0) = o0;
    *(float4*)(y + (size_t)t * DD + d0 + 4) = o1;
}

extern "C" void kernel_launch(void* const* d_in, const int* in_sizes, int n_in,
                              void* d_out, int out_size, void* d_ws, size_t ws_size,
                              hipStream_t stream) {
    (void)in_sizes; (void)n_in; (void)out_size; (void)ws_size;
    const float* x      = (const float*)d_in[0];
    const float* wts    = (const float*)d_in[1];
    const float* w_gu   = (const float*)d_in[2];
    const float* w_dn   = (const float*)d_in[3];
    const float* w_gu_s = (const float*)d_in[4];
    const float* w_dn_s = (const float*)d_in[5];
    const int*   indices= (const int*)d_in[6];
    float* y = (float*)d_out;

    char* ws = (char*)d_ws;
    size_t off = 0;
    auto alloc = [&](size_t bytes) {
        void* p = ws + off;
        off = (off + bytes + 255) & ~(size_t)255;
        return p;
    };
    int*    counts = (int*)alloc((size_t)EE * 4);
    int*    tok    = (int*)alloc((size_t)EE * CC * 4);
    int*    sop    = (int*)alloc((size_t)TT * KK * 4);
    bf16_t* xall   = (bf16_t*)alloc((size_t)(EE * CC + TT) * DD * 2);
    bf16_t* actb   = (bf16_t*)alloc((size_t)(EE * CC + SS * TT) * FF * 2);
    bf16_t* dnout  = (bf16_t*)alloc((size_t)(EE * CC + SS * TT) * DD * 2);

    hipMemsetAsync(counts, 0, EE * 4, stream);
    k_dispatch<<<(TT * KK + 255) / 256, 256, 0, stream>>>(indices, counts, tok, sop);
    k_gather<<<EE * CC + TT, 256, 0, stream>>>(x, tok, xall);

    // ---- gate_up (K=DD, B stride 2*FF), silu fused -> actb ----
    // routed: 32 experts x 88 fused slabs (16 gate + 16 up cols) = 2816 blocks
    k_gemm_r<true><<<EE * 88, 256, 0, stream>>>(xall, w_gu, actb, DD, 2 * FF, FF, 88);
    k_gemm_s<true><<<8 * 6 * 16, 256, 0, stream>>>(
        xall + (size_t)EE * CC * DD, w_gu_s, actb + (size_t)EE * CC * FF,
        DD, 2 * FF, FF, 0, 44, 6, 22);

    // ---- down (K=FF, B stride DD) -> dnout ----
    // routed: 32 experts x 64 slabs (32 cols) = 2048 blocks
    k_gemm_r<false><<<EE * 64, 256, 0, stream>>>(actb, w_dn, dnout, FF, DD, DD, 64);
    k_gemm_s<false><<<8 * 4 * 16, 256, 0, stream>>>(
        actb + (size_t)EE * CC * FF, w_dn_s, dnout + (size_t)EE * CC * DD,
        FF, DD, DD, TT, 32, 4, 16);

    k_combine<<<TT, 256, 0, stream>>>(dnout, sop, wts, y);
}

// Round 12
// 2138.386 us; speedup vs baseline: 1.0188x; 1.0188x over previous
//
#include <hip/hip_runtime.h>
#include <hip/hip_bf16.h>

// Problem constants
#define TT 2048
#define KK 6
#define EE 32
#define DD 2048
#define FF 1408
#define SS 2
#define CC 384   // TT*KK/EE

typedef __bf16 bf16_t;
typedef __attribute__((ext_vector_type(8))) __bf16 bf16x8;
typedef __attribute__((ext_vector_type(4))) float f32x4;
typedef unsigned int u32;
typedef unsigned short u16;

#define AS1 __attribute__((address_space(1)))
#define AS3 __attribute__((address_space(3)))

__device__ __forceinline__ u32 f2bf(float f) {
    u32 u = __builtin_bit_cast(u32, f);
    return (u + 0x7fffu + ((u >> 16) & 1u)) >> 16;   // RNE, no NaN in data
}
__device__ __forceinline__ bf16_t f2bf1(float f) {
    return __builtin_bit_cast(bf16_t, (u16)f2bf(f));
}
__device__ __forceinline__ u32 pack2(float a, float b) {
    return f2bf(a) | (f2bf(b) << 16);
}
__device__ __forceinline__ float silu_mul(float g, float u) {
    return (g / (1.0f + __expf(-g))) * u;
}

// ---------------- dispatch: pair -> slot (balanced: exactly CC per expert) ----
__global__ void k_dispatch(const int* __restrict__ idx, int* __restrict__ counts,
                           int* __restrict__ tok, int* __restrict__ sop) {
    int p = blockIdx.x * 256 + threadIdx.x;
    if (p >= TT * KK) return;
    int e = idx[p];
    int pos = atomicAdd(&counts[e], 1);
    int slot = e * CC + pos;
    tok[slot] = p / KK;
    sop[p] = slot;
}

// ---------------- gather + fp32->bf16 convert --------------------------------
__global__ void k_gather(const float* __restrict__ x, const int* __restrict__ tok,
                         bf16_t* __restrict__ xall) {
    int row = blockIdx.x;
    int srow = (row < EE * CC) ? tok[row] : (row - EE * CC);
    const float* src = x + (size_t)srow * DD;
    bf16_t* dst = xall + (size_t)row * DD;
    int c0 = threadIdx.x * 8;
    float4 a = *(const float4*)(src + c0);
    float4 b = *(const float4*)(src + c0 + 4);
    uint4 o;
    o.x = pack2(a.x, a.y); o.y = pack2(a.z, a.w);
    o.z = pack2(b.x, b.y); o.w = pack2(b.z, b.w);
    *(uint4*)(dst + c0) = o;
}

// =====================================================================
// Weight converter: fp32 [e][K][Nsrc] -> bf16 MFMA-ready panels.
// Panel = (expert, 64-col slab). Within panel, K-step t (32 k):
//   byte off = t*4096 + vcol*64 + kq*16 + (k&7)*2   (kq = (k>>3)&3)
// so a GEMM wave's fragment-j load (lane l: vcol=j*16+(l&15), kq=l>>4)
// covers bytes [t*4096 + j*1024, +1024) -- 1KB CONTIGUOUS per wave-load.
// For gate_up (GU): panel p pairs gate cols [p*32,+32) as vcol 0..31 and
// up cols [FF+p*32,+32) as vcol 32..63 (silu pairing in GEMM epilogue).
// Converter reads LINEARLY (512B/row chunks), stages LDS, writes 1KB chunks.
// =====================================================================
template<bool GU>
__global__ __launch_bounds__(256) void k_conv(
    const float* __restrict__ W, bf16_t* __restrict__ P, int Kd, int Nsrc)
{
    const int q = blockIdx.x, t = blockIdx.y, e = blockIdx.z;
    const int tid = threadIdx.x;
    const int ks = Kd >> 5;
    const int npan = GU ? 44 : 32;
    __shared__ bf16_t ls[32][132];

    // ---- ingest: rows t*32..+32, cols q*128..+128 (coalesced float4) ----
    {
        const int r = tid >> 3, g = tid & 7;     // 8 threads/row, 16 cols each
        const float* sp = W + ((size_t)e * Kd + t * 32 + r) * Nsrc + q * 128 + g * 16;
        #pragma unroll
        for (int f = 0; f < 4; ++f) {
            float4 v = *(const float4*)(sp + f * 4);
            ls[r][g * 16 + f * 4 + 0] = f2bf1(v.x);
            ls[r][g * 16 + f * 4 + 1] = f2bf1(v.y);
            ls[r][g * 16 + f * 4 + 2] = f2bf1(v.z);
            ls[r][g * 16 + f * 4 + 3] = f2bf1(v.w);
        }
    }
    __syncthreads();

    // ---- emit: 512 units of 16B; consecutive tid -> contiguous dest ----
    #pragma unroll
    for (int it = 0; it < 2; ++it) {
        const int u = tid + it * 256;
        const int c = u >> 2, kq = u & 3;        // c 0..127, kq 0..3
        bf16x8 o;
        #pragma unroll
        for (int jj = 0; jj < 8; ++jj) o[jj] = ls[kq * 8 + jj][c];
        const int csrc = q * 128 + c;
        int panel, vcol;
        if (GU) {
            if (csrc < FF) { panel = csrc >> 5;            vcol = csrc & 31; }
            else           { int cu = csrc - FF; panel = cu >> 5; vcol = 32 + (cu & 31); }
        } else {
            panel = csrc >> 6; vcol = csrc & 63;
        }
        bf16_t* dst = P + ((size_t)e * npan + panel) * ((size_t)ks * 2048)
                        + (size_t)t * 2048 + vcol * 32 + kq * 8;
        *(bf16x8*)dst = o;
    }
}

// =====================================================================
// Routed grouped GEMM: ZERO LDS, ZERO barriers.
// Block = (expert, panel), 512 thr (8 waves); wave-tile 48x64, M=384 ->
// B panel fetched once (first wave misses to HBM, siblings hit L2).
// B fragments: 1KB-contiguous wave-loads from the bf16 panel (linear
// stream across the K-loop -- the fill's 6.4TB/s regime). A fragments
// direct from L2/L3-resident bf16 activations. Compiler pipelines freely
// (no barriers); acc[3][4]=48 regs -> no occupancy cliff.
// =====================================================================
template<bool FUSED>
__global__ __launch_bounds__(512, 4) void k_gemm_r(
    const bf16_t* __restrict__ Aall, const bf16_t* __restrict__ Pan,
    bf16_t* __restrict__ Out, int Kdim, int Ostr, int NB)
{
    const int lin = blockIdx.x;
    const int xcd = lin & 7, jj = lin >> 3;
    const int e = xcd + 8 * (jj / NB);     // expert pinned to XCD e%8
    const int p = jj % NB;
    const int ks = Kdim >> 5;

    const bf16_t* A = Aall + (size_t)e * CC * Kdim;
    const bf16_t* P = Pan + ((size_t)e * NB + p) * ((size_t)ks * 2048);

    const int tid = threadIdx.x;
    const int lane = tid & 63, wid = tid >> 6;
    const int l15 = lane & 15, lq = lane >> 4;
    const int m_base = wid * 48;               // 8 waves x 48 rows = 384

    const bf16_t* ap0 = A + (size_t)(m_base + 0 * 16 + l15) * Kdim + lq * 8;
    const bf16_t* ap1 = A + (size_t)(m_base + 1 * 16 + l15) * Kdim + lq * 8;
    const bf16_t* ap2 = A + (size_t)(m_base + 2 * 16 + l15) * Kdim + lq * 8;
    const bf16_t* bp  = P + (size_t)(l15 * 32 + lq * 8);   // lane base in panel

    f32x4 acc[3][4] = {};

    #pragma unroll 2
    for (int t = 0; t < ks; ++t) {
        bf16x8 bfr[4], af[3];
        #pragma unroll
        for (int j = 0; j < 4; ++j)
            bfr[j] = *(const bf16x8*)(bp + (size_t)t * 2048 + j * 512);
        af[0] = *(const bf16x8*)(ap0 + (size_t)t * 32);
        af[1] = *(const bf16x8*)(ap1 + (size_t)t * 32);
        af[2] = *(const bf16x8*)(ap2 + (size_t)t * 32);
        #pragma unroll
        for (int m = 0; m < 3; ++m)
            #pragma unroll
            for (int j = 0; j < 4; ++j)
                acc[m][j] = __builtin_amdgcn_mfma_f32_16x16x32_bf16(
                    m == 0 ? af[0] : (m == 1 ? af[1] : af[2]), bfr[j], acc[m][j], 0, 0, 0);
    }

    // ---- epilogue: C/D layout col=lane&15, row=quad*4+reg ----
    if (FUSED) {   // vcol 0..31 = gate cols p*32+., vcol 32..63 = matching up
        bf16_t* Cout = Out + (size_t)e * CC * Ostr + p * 32;
        #pragma unroll
        for (int m = 0; m < 3; ++m)
            #pragma unroll
            for (int j = 0; j < 2; ++j) {
                const int n = j * 16 + l15;
                #pragma unroll
                for (int rr = 0; rr < 4; ++rr) {
                    const int mm = m_base + m * 16 + lq * 4 + rr;
                    Cout[(size_t)mm * Ostr + n] =
                        (bf16_t)silu_mul(acc[m][j][rr], acc[m][j + 2][rr]);
                }
            }
    } else {
        bf16_t* Cout = Out + (size_t)e * CC * Ostr + p * 64;
        #pragma unroll
        for (int m = 0; m < 3; ++m)
            #pragma unroll
            for (int j = 0; j < 4; ++j) {
                const int n = j * 16 + l15;
                #pragma unroll
                for (int rr = 0; rr < 4; ++rr) {
                    const int mm = m_base + m * 16 + lq * 4 + rr;
                    Cout[(size_t)mm * Ostr + n] = (bf16_t)acc[m][j][rr];
                }
            }
    }
}

// =====================================================================
// Shared-expert GEMM. 256 threads (4 waves, 2m x 2n), 128x128, BK=32.
// R8-verified static-ring pipeline, verbatim (fp32 weights, small).
// =====================================================================
#define BSTR 40
template<bool FUSED>
__global__ __launch_bounds__(256) void k_gemm_s(
    const bf16_t* __restrict__ Ash, const float* __restrict__ Bsh,
    bf16_t* __restrict__ Out, int Kdim, int Bstr, int Ostr, int ash_stride,
    int nkeys, int KQ, int NBs)
{
    const int b = blockIdx.x;
    const int xcd = b & 7, jj = b >> 3;
    const int m = jj / KQ, kqi = jj % KQ;
    const int key = kqi * 8 + xcd;
    if (key >= nkeys) return;
    const int s = key / NBs, nb = key % NBs;

    const bf16_t* A = Ash + ((size_t)s * ash_stride + (size_t)m * 128) * Kdim;
    const float* Bp = Bsh + (size_t)s * Kdim * Bstr;

    const int tid = threadIdx.x;
    const int lane = tid & 63, wid = tid >> 6;
    const int m_off = (wid >> 1) * 64, wn = wid & 1;
    const int l15 = lane & 15, lq = lane >> 4;
    const int arow = tid >> 2, ac = tid & 3;
    const int bn = tid & 127, kh = tid >> 7;

    const float* bsrc;
    bf16_t* Cout;
    if (FUSED) {
        bsrc = Bp + ((bn & 64) ? FF : 0) + nb * 64 + (bn & 63);
        Cout = Out + ((size_t)s * TT + (size_t)m * 128) * Ostr + nb * 64;
    } else {
        bsrc = Bp + nb * 128 + bn;
        Cout = Out + ((size_t)s * TT + (size_t)m * 128) * Ostr + nb * 128;
    }

    __shared__ __align__(16) bf16_t As[2][128 * 32];
    __shared__ __align__(16) bf16_t Bs[2][128 * BSTR];

    f32x4 acc[4][4] = {};
    const int ks = Kdim >> 5;

    auto stageA = [&](int kt, bf16_t* dst) {
        const int k0 = kt << 5;
        #pragma unroll
        for (int i = 0; i < 2; ++i) {
            const int row = i * 64 + arow;
            const int c = ac ^ (arow & 3);
            const bf16_t* g = A + (size_t)row * Kdim + (k0 + c * 8);
            AS3 u32* l = (AS3 u32*)(void*)(dst + (size_t)(i * 64 + wid * 16) * 32);
            __builtin_amdgcn_global_load_lds((const AS1 u32*)(const void*)g, l, 16, 0, 0);
        }
    };
    auto loadB = [&](int kt, float* v) {
        const float* sp = bsrc + (size_t)((kt << 5) + kh * 16) * Bstr;
        #pragma unroll
        for (int t = 0; t < 16; ++t) v[t] = sp[(size_t)t * Bstr];
    };
    auto writeB = [&](bf16_t* bbuf, const float* v) {
        u32 p[8];
        #pragma unroll
        for (int t = 0; t < 8; ++t) p[t] = pack2(v[2 * t], v[2 * t + 1]);
        uint4 w0, w1;
        w0.x = p[0]; w0.y = p[1]; w0.z = p[2]; w0.w = p[3];
        w1.x = p[4]; w1.y = p[5]; w1.z = p[6]; w1.w = p[7];
        *(uint4*)(bbuf + (size_t)bn * BSTR + kh * 16) = w0;
        *(uint4*)(bbuf + (size_t)bn * BSTR + kh * 16 + 8) = w1;
    };
    auto compute = [&](const bf16_t* abuf, const bf16_t* bbuf) {
        bf16x8 af[4], bfr[4];
        #pragma unroll
        for (int i = 0; i < 4; ++i) {
            const int row = m_off + i * 16 + l15;
            af[i] = *(const bf16x8*)(abuf + (size_t)row * 32
                       + (size_t)((lq ^ (row & 3)) * 8));
        }
        #pragma unroll
        for (int j = 0; j < 4; ++j) {
            const int n_ds = FUSED ? (wn * 32 + (j & 1) * 16 + (j >> 1) * 64)
                                   : (wn * 64 + j * 16);
            bfr[j] = *(const bf16x8*)(bbuf + (size_t)(n_ds + l15) * BSTR + lq * 8);
        }
        #pragma unroll
        for (int i = 0; i < 4; ++i)
            #pragma unroll
            for (int j = 0; j < 4; ++j)
                acc[i][j] = __builtin_amdgcn_mfma_f32_16x16x32_bf16(af[i], bfr[j], acc[i][j], 0, 0, 0);
    };

    float r0[16], r1[16], r2[16], r3[16];
    bf16_t* const As0 = &As[0][0];  bf16_t* const As1 = &As[1][0];
    bf16_t* const Bs0 = &Bs[0][0];  bf16_t* const Bs1 = &Bs[1][0];

    loadB(0, r0);
    asm volatile("s_waitcnt vmcnt(0)" ::: "memory");
    writeB(Bs0, r0);
    loadB(1, r1);
    loadB(2, r2);
    stageA(0, As0);
    loadB(3, r3);

#define S_ITER(T, RLOAD, RWRITE, ASC, ASN, BSC, BSN)                      \
    {                                                                     \
        const int tb = ((T) + 4 < ks) ? (T) + 4 : ks - 1;                 \
        loadB(tb, RLOAD);                                                 \
        asm volatile("s_waitcnt vmcnt(32)" ::: "memory");                 \
        asm volatile("s_waitcnt lgkmcnt(0)" ::: "memory");                \
        __builtin_amdgcn_s_barrier();                                     \
        const int tn = ((T) + 1 < ks) ? (T) + 1 : ks - 1;                 \
        stageA(tn, ASN);                                                  \
        compute(ASC, BSC);                                                \
        writeB(BSN, RWRITE);                                              \
    }

    for (int t = 0; t < ks; t += 4) {
        S_ITER(t + 0, r0, r1, As0, As1, Bs0, Bs1);
        S_ITER(t + 1, r1, r2, As1, As0, Bs1, Bs0);
        S_ITER(t + 2, r2, r3, As0, As1, Bs0, Bs1);
        S_ITER(t + 3, r3, r0, As1, As0, Bs1, Bs0);
    }
#undef S_ITER

    if (FUSED) {
        #pragma unroll
        for (int i = 0; i < 4; ++i)
            #pragma unroll
            for (int j = 0; j < 2; ++j) {
                const int n = wn * 32 + j * 16 + l15;
                #pragma unroll
                for (int rr = 0; rr < 4; ++rr) {
                    const int mm = m_off + i * 16 + lq * 4 + rr;
                    Cout[(size_t)mm * Ostr + n] = (bf16_t)silu_mul(acc[i][j][rr], acc[i][j + 2][rr]);
                }
            }
    } else {
        #pragma unroll
        for (int i = 0; i < 4; ++i)
            #pragma unroll
            for (int j = 0; j < 4; ++j) {
                const int n = wn * 64 + j * 16 + l15;
                #pragma unroll
                for (int rr = 0; rr < 4; ++rr) {
                    const int mm = m_off + i * 16 + lq * 4 + rr;
                    Cout[(size_t)mm * Ostr + n] = (bf16_t)acc[i][j][rr];
                }
            }
    }
}

// ---------------- combine: weighted scatter of routed + shared add ----------
__global__ void k_combine(const bf16_t* __restrict__ down, const int* __restrict__ sop,
                          const float* __restrict__ wts, float* __restrict__ y) {
    int t = blockIdx.x;
    int d0 = threadIdx.x * 8;
    float a[8] = {0, 0, 0, 0, 0, 0, 0, 0};
    #pragma unroll
    for (int k = 0; k < KK; ++k) {
        int slot = sop[t * KK + k];
        float w = wts[t * KK + k];
        bf16x8 v = *(const bf16x8*)(down + (size_t)slot * DD + d0);
        #pragma unroll
        for (int j = 0; j < 8; ++j) a[j] += w * (float)v[j];
    }
    #pragma unroll
    for (int s = 0; s < SS; ++s) {
        bf16x8 v = *(const bf16x8*)(down + ((size_t)EE * CC + (size_t)s * TT + t) * DD + d0);
        #pragma unroll
        for (int j = 0; j < 8; ++j) a[j] += (float)v[j];
    }
    float4 o0, o1;
    o0.x = a[0]; o0.y = a[1]; o0.z = a[2]; o0.w = a[3];
    o1.x = a[4]; o1.y = a[5]; o1.z = a[6]; o1.w = a[7];
    *(float4*)(y + (size_t)t * DD + d0) = o0;
    *(float4*)(y + (size_t)t * DD + d0 + 4) = o1;
}

extern "C" void kernel_launch(void* const* d_in, const int* in_sizes, int n_in,
                              void* d_out, int out_size, void* d_ws, size_t ws_size,
                              hipStream_t stream) {
    (void)in_sizes; (void)n_in; (void)out_size; (void)ws_size;
    const float* x      = (const float*)d_in[0];
    const float* wts    = (const float*)d_in[1];
    const float* w_gu   = (const float*)d_in[2];
    const float* w_dn   = (const float*)d_in[3];
    const float* w_gu_s = (const float*)d_in[4];
    const float* w_dn_s = (const float*)d_in[5];
    const int*   indices= (const int*)d_in[6];
    float* y = (float*)d_out;

    char* ws = (char*)d_ws;
    size_t off = 0;
    auto alloc = [&](size_t bytes) {
        void* p = ws + off;
        off = (off + bytes + 255) & ~(size_t)255;
        return p;
    };
    int*    counts = (int*)alloc((size_t)EE * 4);
    int*    tok    = (int*)alloc((size_t)EE * CC * 4);
    int*    sop    = (int*)alloc((size_t)TT * KK * 4);
    bf16_t* xall   = (bf16_t*)alloc((size_t)(EE * CC + TT) * DD * 2);
    bf16_t* actb   = (bf16_t*)alloc((size_t)(EE * CC + SS * TT) * FF * 2);
    bf16_t* dnout  = (bf16_t*)alloc((size_t)(EE * CC + SS * TT) * DD * 2);
    bf16_t* gup    = (bf16_t*)alloc((size_t)EE * 44 * DD * 64 * 2);   // 369 MB panels
    bf16_t* dnp    = (bf16_t*)alloc((size_t)EE * 32 * FF * 64 * 2);   // 185 MB panels

    hipMemsetAsync(counts, 0, EE * 4, stream);
    k_dispatch<<<(TT * KK + 255) / 256, 256, 0, stream>>>(indices, counts, tok, sop);
    k_gather<<<EE * CC + TT, 256, 0, stream>>>(x, tok, xall);

    // ---- weight conversion: fp32 -> bf16 MFMA panels (linear streams) ----
    k_conv<true><<<dim3(22, 64, EE), 256, 0, stream>>>(w_gu, gup, DD, 2 * FF);
    k_conv<false><<<dim3(16, 44, EE), 256, 0, stream>>>(w_dn, dnp, FF, DD);

    // ---- gate_up (K=DD), silu fused -> actb ----
    k_gemm_r<true><<<EE * 44, 512, 0, stream>>>(xall, gup, actb, DD, FF, 44);
    k_gemm_s<true><<<8 * 6 * 16, 256, 0, stream>>>(
        xall + (size_t)EE * CC * DD, w_gu_s, actb + (size_t)EE * CC * FF,
        DD, 2 * FF, FF, 0, 44, 6, 22);

    // ---- down (K=FF) -> dnout ----
    k_gemm_r<false><<<EE * 32, 512, 0, stream>>>(actb, dnp, dnout, FF, DD, 32);
    k_gemm_s<false><<<8 * 4 * 16, 256, 0, stream>>>(
        actb + (size_t)EE * CC * FF, w_dn_s, dnout + (size_t)EE * CC * DD,
        FF, DD, DD, TT, 32, 4, 16);

    k_combine<<<TT, 256, 0, stream>>>(dnout, sop, wts, y);
}